// Round 2
// baseline (1197.557 us; speedup 1.0000x reference)
//
#include <hip/hip_runtime.h>
#include <math.h>

// B=32, R=16384, C=16, IC=16, OC=16, 3 routing iterations.
// x: (B,C,IC) fp32 [8192]; W: (R,C,OC,IC) fp32 [67108864 = 256 MB]; out: (B,C,OC) fp32.

#define RT 16384

typedef const __attribute__((address_space(1))) void GV;
typedef __attribute__((address_space(3))) void LV;

__device__ __forceinline__ float rfl(float v) {
    return __int_as_float(__builtin_amdgcn_readfirstlane(__float_as_int(v)));
}

// ---------------------------------------------------------------------------
// K1: wsum[c,o,i] = sum_r W[r,c,o,i].  W = 16,777,216 float4s.
// ---------------------------------------------------------------------------
__global__ __launch_bounds__(256) void k_wsum(const float4* __restrict__ W4,
                                              float* __restrict__ wsum) {
    int gid = blockIdx.x * 256 + threadIdx.x;      // [0, 262144)
    float4 acc = {0.f, 0.f, 0.f, 0.f};
    int idx = gid;
    #pragma unroll
    for (int it = 0; it < 64; ++it) {              // 16777216 / 262144 = 64
        float4 w = W4[idx];
        acc.x += w.x; acc.y += w.y; acc.z += w.z; acc.w += w.w;
        idx += 262144;
    }
    int cls = gid & 1023;                          // (c,o,i4) within an r-block
    atomicAdd(&wsum[cls * 4 + 0], acc.x);
    atomicAdd(&wsum[cls * 4 + 1], acc.y);
    atomicAdd(&wsum[cls * 4 + 2], acc.z);
    atomicAdd(&wsum[cls * 4 + 3], acc.w);
}

// ---------------------------------------------------------------------------
// K2: s1 = (1/R) * wsum . x ;  v1 = squash(s1)  -> v1[b*256 + c*16 + o]
// ---------------------------------------------------------------------------
__global__ __launch_bounds__(256) void k_v1(const float* __restrict__ wsum,
                                            const float* __restrict__ x,
                                            float* __restrict__ v1) {
    int t = blockIdx.x * 256 + threadIdx.x;        // 0..8191
    int o = t & 15, c = (t >> 4) & 15, b = t >> 8;
    const float* xb = x + (b * 16 + c) * 16;
    const float* wr = wsum + (c * 16 + o) * 16;
    float s = 0.f;
    #pragma unroll
    for (int i = 0; i < 16; ++i) s += wr[i] * xb[i];
    s *= (1.0f / 16384.0f);
    float ns = s * s;
    #pragma unroll
    for (int d = 1; d < 16; d <<= 1) ns += __shfl_xor(ns, d);
    v1[t] = s * (sqrtf(ns) / (1.0f + ns));
}

// ---------------------------------------------------------------------------
// K4: s = E/Z, v = squash(s) -> dst (v2 buffer or final out)
// ---------------------------------------------------------------------------
__global__ __launch_bounds__(256) void k_vout(const float* __restrict__ E,
                                              const float* __restrict__ Z,
                                              float* __restrict__ dst) {
    int t = blockIdx.x * 256 + threadIdx.x;        // 0..8191
    float s = E[t] / Z[t >> 4];                    // t>>4 = b*16+c
    float ns = s * s;
    #pragma unroll
    for (int d = 1; d < 16; d <<= 1) ns += __shfl_xor(ns, d);
    dst[t] = s * (sqrtf(ns) / (1.0f + ns));
}

// ---------------------------------------------------------------------------
// K3: fused routing pass.  For each (b,c,r):
//   u[o]  = sum_i W[r,c,o,i] * x[b,c,i]
//   L     = sum_o u[o] * v[b,c,o]  (+ Lprev if PASS3)
//   e     = exp(L) ; E[b,c,o] += e*u[o] ; Z[b,c] += e
//
// o-split layout (fits 128 VGPR -> no scratch):
//   lane = (h, lr): half h owns o in [8h, 8h+8), row lr of a 32-row chunk.
//   Per-lane regs: u[4][8] + accE[4][8] + vsel[4][8] + w-frag 16 ~= 120.
//   Lv recombined across halves with one __shfl_xor(p, 32); e identical in
//   both halves (accZ scaled 0.5 at the end; L written by half 0 only).
//   x in SGPRs (readfirstlane); 2 x 32 KB double-buffered LDS -> 2 blocks/CU.
//   global_load_lds width-16 staging, XOR swizzle on the GLOBAL source addr
//   (linear LDS dest); read index = (lr*65 ^ (h<<5)) ^ const, one v_xor each.
// ---------------------------------------------------------------------------
template <int PASS3>
__global__ __launch_bounds__(512, 4)
void k_iter(const float* __restrict__ W,
            const float* __restrict__ x,
            const float* __restrict__ v,
            float* __restrict__ L,
            float* __restrict__ E,
            float* __restrict__ Z) {
    __shared__ float4 Wl[2][32 * 64];              // 64 KB: 2 x (32 rows x 1 KB)

    int c = blockIdx.y;
    int r0 = blockIdx.x * 256;
    int tid = threadIdx.x, wv = tid >> 6, lane = tid & 63;
    int h = lane >> 5, lr = lane & 31;

    const float4* W4c = (const float4*)W + (size_t)c * 64;   // row r at +r*1024

    // x rows for this wave's 4 b's -> SGPRs (wave-uniform)
    float xs[4][16];
    #pragma unroll
    for (int bl = 0; bl < 4; ++bl) {
        const float4* xb = (const float4*)(x + ((wv * 4 + bl) * 16 + c) * 16);
        #pragma unroll
        for (int j = 0; j < 4; ++j) {
            float4 xv = xb[j];
            xs[bl][j * 4 + 0] = rfl(xv.x);
            xs[bl][j * 4 + 1] = rfl(xv.y);
            xs[bl][j * 4 + 2] = rfl(xv.z);
            xs[bl][j * 4 + 3] = rfl(xv.w);
        }
    }

    // vsel[bl][oh] = v[b, c, h*8 + oh]  (this half's 8 v components)
    float vsel[4][8];
    #pragma unroll
    for (int bl = 0; bl < 4; ++bl) {
        const float4* vb = (const float4*)(v + ((wv * 4 + bl) * 16 + c) * 16);
        float4 a = vb[h * 2 + 0], d = vb[h * 2 + 1];
        vsel[bl][0] = a.x; vsel[bl][1] = a.y; vsel[bl][2] = a.z; vsel[bl][3] = a.w;
        vsel[bl][4] = d.x; vsel[bl][5] = d.y; vsel[bl][6] = d.z; vsel[bl][7] = d.w;
    }

    float accE[4][8];
    float accZ[4] = {0.f, 0.f, 0.f, 0.f};
    #pragma unroll
    for (int bl = 0; bl < 4; ++bl)
        #pragma unroll
        for (int oh = 0; oh < 8; ++oh) accE[bl][oh] = 0.f;

    // stage chunk cn (32 rows) into buffer tb: each wave stages 4 rows
#define STAGE(tb, cn) {                                                        \
        int rb = r0 + (cn) * 32;                                               \
        _Pragma("unroll")                                                      \
        for (int k = 0; k < 4; ++k) {                                          \
            int row = k * 8 + wv;                                              \
            const float4* src = W4c + (size_t)(rb + row) * 1024 + (lane ^ row);\
            __builtin_amdgcn_global_load_lds((GV*)src,                         \
                (LV*)&Wl[tb][row * 64], 16, 0, 0);                             \
        } }

    STAGE(0, 0);
    __syncthreads();

    int vlidx = (lr * 65) ^ (h << 5);              // swizzled read base (float4 idx)

    #pragma unroll
    for (int chunk = 0; chunk < 8; ++chunk) {
        int buf = chunk & 1;
        if (chunk < 7) STAGE(buf ^ 1, chunk + 1);  // prefetch next (in flight)

        const float4* Wlb = &Wl[buf][0];
        float u[4][8];
        #pragma unroll
        for (int oh = 0; oh < 8; ++oh) {
            float4 w0 = Wlb[vlidx ^ (oh * 4 + 0)];
            float4 w1 = Wlb[vlidx ^ (oh * 4 + 1)];
            float4 w2 = Wlb[vlidx ^ (oh * 4 + 2)];
            float4 w3 = Wlb[vlidx ^ (oh * 4 + 3)];
            #pragma unroll
            for (int bl = 0; bl < 4; ++bl) {
                u[bl][oh] =
                    w0.x*xs[bl][0]  + w0.y*xs[bl][1]  + w0.z*xs[bl][2]  + w0.w*xs[bl][3]  +
                    w1.x*xs[bl][4]  + w1.y*xs[bl][5]  + w1.z*xs[bl][6]  + w1.w*xs[bl][7]  +
                    w2.x*xs[bl][8]  + w2.y*xs[bl][9]  + w2.z*xs[bl][10] + w2.w*xs[bl][11] +
                    w3.x*xs[bl][12] + w3.y*xs[bl][13] + w3.z*xs[bl][14] + w3.w*xs[bl][15];
            }
        }

        int r = r0 + chunk * 32 + lr;
        #pragma unroll
        for (int bl = 0; bl < 4; ++bl) {
            float p =
                u[bl][0]*vsel[bl][0] + u[bl][1]*vsel[bl][1] +
                u[bl][2]*vsel[bl][2] + u[bl][3]*vsel[bl][3] +
                u[bl][4]*vsel[bl][4] + u[bl][5]*vsel[bl][5] +
                u[bl][6]*vsel[bl][6] + u[bl][7]*vsel[bl][7];
            float Lv = p + __shfl_xor(p, 32);      // combine the two o-halves
            size_t li = (size_t)((wv * 4 + bl) * 16 + c) * RT + r;
            if (PASS3) Lv += L[li];
            else if (h == 0) L[li] = Lv;
            float e = __expf(Lv);
            accZ[bl] += e;                         // counted twice (both halves)
            #pragma unroll
            for (int oh = 0; oh < 8; ++oh) accE[bl][oh] += e * u[bl][oh];
        }
        __syncthreads();
    }
#undef STAGE

    // Reduce accE over the 32 rows of each half (butterfly d<32 stays in-half).
    float va = 0.f;
    #pragma unroll
    for (int bl = 0; bl < 4; ++bl) {
        #pragma unroll
        for (int oh = 0; oh < 8; ++oh) {
            float t = accE[bl][oh];
            #pragma unroll
            for (int d = 1; d < 32; d <<= 1) t += __shfl_xor(t, d);
            if (lr == bl * 8 + oh) va = t;
        }
    }
    float vz = 0.f;
    #pragma unroll
    for (int bl = 0; bl < 4; ++bl) {
        float t = accZ[bl];
        #pragma unroll
        for (int d = 1; d < 64; d <<= 1) t += __shfl_xor(t, d);
        if (lane == bl) vz = t;
    }
    int b = wv * 4 + (lr >> 3);
    int o = h * 8 + (lr & 7);
    atomicAdd(&E[b * 256 + c * 16 + o], va);
    if (lane < 4) atomicAdd(&Z[(wv * 4 + lane) * 16 + c], vz * 0.5f);
}

// ---------------------------------------------------------------------------
// launch
// ---------------------------------------------------------------------------
extern "C" void kernel_launch(void* const* d_in, const int* in_sizes, int n_in,
                              void* d_out, int out_size, void* d_ws, size_t ws_size,
                              hipStream_t stream) {
    const float* x = (const float*)d_in[0];        // 8192 floats
    const float* W = (const float*)d_in[1];        // 67108864 floats (256 MB)
    float* out = (float*)d_out;                    // 8192 floats
    float* ws = (float*)d_ws;

    float* wsum = ws + 0;          // 4096
    float* E2   = ws + 4096;       // 8192
    float* Z2   = ws + 12288;      // 512
    float* E3   = ws + 12800;      // 8192
    float* Z3   = ws + 20992;      // 512   (accumulated region ends at 21504)
    float* v1   = ws + 21504;      // 8192
    float* v2   = ws + 29696;      // 8192
    float* L    = ws + 37888;      // 8388608 (33.5 MB)

    hipMemsetAsync(ws, 0, 21504 * sizeof(float), stream);

    // iter 1: uniform softmax -> v1 from Wsum (W pass 1)
    k_wsum<<<1024, 256, 0, stream>>>((const float4*)W, wsum);
    k_v1<<<32, 256, 0, stream>>>(wsum, x, v1);

    // iter 2 fused: L2 = <u, v1>, E2/Z2 accumulated in-pass (W pass 2)
    k_iter<0><<<dim3(64, 16), 512, 0, stream>>>(W, x, v1, L, E2, Z2);
    k_vout<<<32, 256, 0, stream>>>(E2, Z2, v2);    // v2 = squash(E2/Z2)

    // iter 3 fused: L3 = L2 + <u, v2>, E3/Z3 accumulated (W pass 3)
    k_iter<1><<<dim3(64, 16), 512, 0, stream>>>(W, x, v2, L, E3, Z3);
    k_vout<<<32, 256, 0, stream>>>(E3, Z3, out);   // out = squash(E3/Z3)
}

// Round 3
// 312.276 us; speedup vs baseline: 3.8349x; 3.8349x over previous
//
#include <hip/hip_runtime.h>
#include <math.h>

// B=32, R=16384, C=16, IC=16, OC=16, 3 routing iterations.
// x: (B,C,IC) fp32 [8192]; W: (R,C,OC,IC) fp32 [67108864 = 256 MB]; out: (B,C,OC) fp32.
//
// Key algebra: logits are linear in v with the same u_hat each pass:
//   L2 = <u, v1>,  L3 = L2 + <u, v2> = <u, v1 + v2>
// so pass 3 is the SAME kernel as pass 2 fed with vs = v1 + v2 -> no L array.

#define RT 16384

typedef const __attribute__((address_space(1))) void GV;
typedef __attribute__((address_space(3))) void LV;

__device__ __forceinline__ float rfl(float v) {
    return __int_as_float(__builtin_amdgcn_readfirstlane(__float_as_int(v)));
}

// ---------------------------------------------------------------------------
// K1: wsum[c,o,i] = sum_r W[r,c,o,i].  W = 16,777,216 float4s.
// ---------------------------------------------------------------------------
__global__ __launch_bounds__(256) void k_wsum(const float4* __restrict__ W4,
                                              float* __restrict__ wsum) {
    int gid = blockIdx.x * 256 + threadIdx.x;      // [0, 262144)
    float4 acc = {0.f, 0.f, 0.f, 0.f};
    int idx = gid;
    #pragma unroll
    for (int it = 0; it < 64; ++it) {              // 16777216 / 262144 = 64
        float4 w = W4[idx];
        acc.x += w.x; acc.y += w.y; acc.z += w.z; acc.w += w.w;
        idx += 262144;
    }
    int cls = gid & 1023;                          // (c,o,i4) within an r-block
    atomicAdd(&wsum[cls * 4 + 0], acc.x);
    atomicAdd(&wsum[cls * 4 + 1], acc.y);
    atomicAdd(&wsum[cls * 4 + 2], acc.z);
    atomicAdd(&wsum[cls * 4 + 3], acc.w);
}

// ---------------------------------------------------------------------------
// K2: s1 = (1/R) * wsum . x ;  v1 = squash(s1)  -> v1[b*256 + c*16 + o]
// ---------------------------------------------------------------------------
__global__ __launch_bounds__(256) void k_v1(const float* __restrict__ wsum,
                                            const float* __restrict__ x,
                                            float* __restrict__ v1) {
    int t = blockIdx.x * 256 + threadIdx.x;        // 0..8191
    int o = t & 15, c = (t >> 4) & 15, b = t >> 8;
    const float* xb = x + (b * 16 + c) * 16;
    const float* wr = wsum + (c * 16 + o) * 16;
    float s = 0.f;
    #pragma unroll
    for (int i = 0; i < 16; ++i) s += wr[i] * xb[i];
    s *= (1.0f / 16384.0f);
    float ns = s * s;
    #pragma unroll
    for (int d = 1; d < 16; d <<= 1) ns += __shfl_xor(ns, d);
    v1[t] = s * (sqrtf(ns) / (1.0f + ns));
}

// ---------------------------------------------------------------------------
// K4a: v2 = squash(E/Z); vs = v1 + v2   (input to pass 3)
// ---------------------------------------------------------------------------
__global__ __launch_bounds__(256) void k_vout_vs(const float* __restrict__ E,
                                                 const float* __restrict__ Z,
                                                 const float* __restrict__ v1,
                                                 float* __restrict__ vs) {
    int t = blockIdx.x * 256 + threadIdx.x;        // 0..8191
    float s = E[t] / Z[t >> 4];                    // t>>4 = b*16+c
    float ns = s * s;
    #pragma unroll
    for (int d = 1; d < 16; d <<= 1) ns += __shfl_xor(ns, d);
    vs[t] = v1[t] + s * (sqrtf(ns) / (1.0f + ns));
}

// ---------------------------------------------------------------------------
// K4b: out = squash(E/Z)
// ---------------------------------------------------------------------------
__global__ __launch_bounds__(256) void k_vout(const float* __restrict__ E,
                                              const float* __restrict__ Z,
                                              float* __restrict__ dst) {
    int t = blockIdx.x * 256 + threadIdx.x;        // 0..8191
    float s = E[t] / Z[t >> 4];
    float ns = s * s;
    #pragma unroll
    for (int d = 1; d < 16; d <<= 1) ns += __shfl_xor(ns, d);
    dst[t] = s * (sqrtf(ns) / (1.0f + ns));
}

// ---------------------------------------------------------------------------
// K3: fused routing pass.  For each (b,c,r):
//   u[o] = sum_i W[r,c,o,i]*x[b,c,i];  Lv = sum_o u[o]*v[b,c,o]
//   e = exp(Lv);  E[b,c,o] += e*u[o];  Z[b,c] += e
//
// o-split layout, sized to FIT 128 VGPRs (R1/R2 post-mortem: the allocator
// gives 128 for __launch_bounds__(512) and spills anything above it):
//   lane = (h, lr): half h owns o in [8h,8h+8), row lr of a 32-row chunk.
//   Live VGPRs: u[4][8]=32 + accE[4][8]=32 + w-frag 16 + temps ~12 = ~92.
//   x in SGPRs (readfirstlane);  v in 2 KB LDS (broadcast ds_read_b128, kept
//   out of VGPRs on purpose);  Lv recombined across halves via shfl_xor(32);
//   accZ double-counted -> x0.5 at the atomic.
//   2 x 32 KB double-buffered LDS -> 2 blocks/CU; global_load_lds width-16
//   staging with XOR swizzle on the GLOBAL source addr (linear LDS dest);
//   swizzled read base (lr*65 ^ h<<5), one v_xor per ds_read_b128, 0 conflicts.
// ---------------------------------------------------------------------------
__global__ __launch_bounds__(512)
void k_iter(const float* __restrict__ W,
            const float* __restrict__ x,
            const float* __restrict__ v,
            float* __restrict__ E,
            float* __restrict__ Z) {
    __shared__ float4 Wl[2][32 * 64];              // 64 KB: 2 x (32 rows x 1 KB)
    __shared__ float4 Vl[128];                     // v[b][o] for this c (2 KB)

    int c = blockIdx.y;
    int r0 = blockIdx.x * 256;
    int tid = threadIdx.x, wv = tid >> 6, lane = tid & 63;
    int h = lane >> 5, lr = lane & 31;

    const float4* W4c = (const float4*)W + (size_t)c * 64;   // row r at +r*1024

    if (tid < 128) {                               // stage v block: Vl[b*4+j]
        int b = tid >> 2, j = tid & 3;
        Vl[tid] = ((const float4*)(v + (b * 16 + c) * 16))[j];
    }

    // x rows for this wave's 4 b's -> SGPRs (wave-uniform)
    float xs[4][16];
    #pragma unroll
    for (int bl = 0; bl < 4; ++bl) {
        const float4* xb = (const float4*)(x + ((wv * 4 + bl) * 16 + c) * 16);
        #pragma unroll
        for (int j = 0; j < 4; ++j) {
            float4 xv = xb[j];
            xs[bl][j * 4 + 0] = rfl(xv.x);
            xs[bl][j * 4 + 1] = rfl(xv.y);
            xs[bl][j * 4 + 2] = rfl(xv.z);
            xs[bl][j * 4 + 3] = rfl(xv.w);
        }
    }

    float accE[4][8];
    float accZ[4] = {0.f, 0.f, 0.f, 0.f};
    #pragma unroll
    for (int bl = 0; bl < 4; ++bl)
        #pragma unroll
        for (int oh = 0; oh < 8; ++oh) accE[bl][oh] = 0.f;

    // stage chunk cn (32 rows) into buffer tb: each wave stages 4 rows
#define STAGE(tb, cn) {                                                        \
        int rb = r0 + (cn) * 32;                                               \
        _Pragma("unroll")                                                      \
        for (int k = 0; k < 4; ++k) {                                          \
            int row = k * 8 + wv;                                              \
            const float4* src = W4c + (size_t)(rb + row) * 1024 + (lane ^ row);\
            __builtin_amdgcn_global_load_lds((GV*)src,                         \
                (LV*)&Wl[tb][row * 64], 16, 0, 0);                             \
        } }

    STAGE(0, 0);
    __syncthreads();

    int vlidx = (lr * 65) ^ (h << 5);              // swizzled read base (float4 idx)

    #pragma unroll
    for (int chunk = 0; chunk < 8; ++chunk) {
        int buf = chunk & 1;
        if (chunk < 7) STAGE(buf ^ 1, chunk + 1);  // prefetch next (in flight)

        const float4* Wlb = &Wl[buf][0];
        float u[4][8];
        #pragma unroll
        for (int oh = 0; oh < 8; ++oh) {
            float4 w0 = Wlb[vlidx ^ (oh * 4 + 0)];
            float4 w1 = Wlb[vlidx ^ (oh * 4 + 1)];
            float4 w2 = Wlb[vlidx ^ (oh * 4 + 2)];
            float4 w3 = Wlb[vlidx ^ (oh * 4 + 3)];
            #pragma unroll
            for (int bl = 0; bl < 4; ++bl) {
                u[bl][oh] =
                    w0.x*xs[bl][0]  + w0.y*xs[bl][1]  + w0.z*xs[bl][2]  + w0.w*xs[bl][3]  +
                    w1.x*xs[bl][4]  + w1.y*xs[bl][5]  + w1.z*xs[bl][6]  + w1.w*xs[bl][7]  +
                    w2.x*xs[bl][8]  + w2.y*xs[bl][9]  + w2.z*xs[bl][10] + w2.w*xs[bl][11] +
                    w3.x*xs[bl][12] + w3.y*xs[bl][13] + w3.z*xs[bl][14] + w3.w*xs[bl][15];
            }
        }

        #pragma unroll
        for (int bl = 0; bl < 4; ++bl) {
            // this half's 8 v components, broadcast from LDS (not VGPR-resident)
            const float4* vb = &Vl[(wv * 4 + bl) * 4 + h * 2];
            float4 va0 = vb[0], va1 = vb[1];
            float p =
                u[bl][0]*va0.x + u[bl][1]*va0.y + u[bl][2]*va0.z + u[bl][3]*va0.w +
                u[bl][4]*va1.x + u[bl][5]*va1.y + u[bl][6]*va1.z + u[bl][7]*va1.w;
            float Lv = p + __shfl_xor(p, 32);      // combine the two o-halves
            float e = __expf(Lv);
            accZ[bl] += e;                         // counted twice (both halves)
            #pragma unroll
            for (int oh = 0; oh < 8; ++oh) accE[bl][oh] += e * u[bl][oh];
        }
        __syncthreads();
    }
#undef STAGE

    // Reduce accE over the 32 rows of each half (butterfly d<32 stays in-half).
    float va = 0.f;
    #pragma unroll
    for (int bl = 0; bl < 4; ++bl) {
        #pragma unroll
        for (int oh = 0; oh < 8; ++oh) {
            float t = accE[bl][oh];
            #pragma unroll
            for (int d = 1; d < 32; d <<= 1) t += __shfl_xor(t, d);
            if (lr == bl * 8 + oh) va = t;
        }
    }
    float vz = 0.f;
    #pragma unroll
    for (int bl = 0; bl < 4; ++bl) {
        float t = accZ[bl];
        #pragma unroll
        for (int d = 1; d < 64; d <<= 1) t += __shfl_xor(t, d);
        if (lane == bl) vz = t;
    }
    int b = wv * 4 + (lr >> 3);
    int o = h * 8 + (lr & 7);
    atomicAdd(&E[b * 256 + c * 16 + o], va);
    if (lane < 4) atomicAdd(&Z[(wv * 4 + lane) * 16 + c], vz * 0.5f);
}

// ---------------------------------------------------------------------------
// launch
// ---------------------------------------------------------------------------
extern "C" void kernel_launch(void* const* d_in, const int* in_sizes, int n_in,
                              void* d_out, int out_size, void* d_ws, size_t ws_size,
                              hipStream_t stream) {
    const float* x = (const float*)d_in[0];        // 8192 floats
    const float* W = (const float*)d_in[1];        // 67108864 floats (256 MB)
    float* out = (float*)d_out;                    // 8192 floats
    float* ws = (float*)d_ws;

    float* wsum = ws + 0;          // 4096
    float* E2   = ws + 4096;       // 8192
    float* Z2   = ws + 12288;      // 512
    float* E3   = ws + 12800;      // 8192
    float* Z3   = ws + 20992;      // 512   (accumulated region ends at 21504)
    float* v1   = ws + 21504;      // 8192
    float* vs   = ws + 29696;      // 8192  (v1 + v2, input to pass 3)

    hipMemsetAsync(ws, 0, 21504 * sizeof(float), stream);

    // iter 1: uniform softmax -> v1 from Wsum (W pass 1)
    k_wsum<<<1024, 256, 0, stream>>>((const float4*)W, wsum);
    k_v1<<<32, 256, 0, stream>>>(wsum, x, v1);

    // iter 2 fused: L2 = <u, v1>, E2/Z2 accumulated in-pass (W pass 2)
    k_iter<<<dim3(64, 16), 512, 0, stream>>>(W, x, v1, E2, Z2);
    k_vout_vs<<<32, 256, 0, stream>>>(E2, Z2, v1, vs);   // vs = v1 + squash(E2/Z2)

    // iter 3 fused: L3 = <u, v1+v2> (linearity: no history buffer needed)
    k_iter<<<dim3(64, 16), 512, 0, stream>>>(W, x, vs, E3, Z3);
    k_vout<<<32, 256, 0, stream>>>(E3, Z3, out);         // out = squash(E3/Z3)
}